// Round 7
// baseline (909.491 us; speedup 1.0000x reference)
//
#include <hip/hip_runtime.h>
#include <stdint.h>

#define B_ 8
#define C_ 256
#define H_ 96
#define W_ 160
#define ND 9
#define NDISP 81
#define YB 3                  // y rows per block
#define CK 2                  // channels per chunk
#define NCHUNK (C_ / CK)      // 128
#define TX 8
#define NXG (W_ / TX)         // 20
#define NTHR 576              // 9 waves
#define NCOMP (YB * ND * NXG) // 540 compute threads
#define ROWS_PER_CH 14        // 3 in1 rows + 11 in2 rows
#define NROWS (CK * ROWS_PER_CH)  // 28
#define ROWSTRIDE 164         // floats (656 B/row)
#define ROWBYTES 656
#define BUF_FLOATS 4608       // 18432 B per buffer = 18 x 1024B DMA slots
#define BUF_BYTES 18432       // multiple of 512 -> swizzle-window safe
#define NBUF 4                // depth-3 prefetch
#define CHSTEP (CK * H_ * W_) // global float step per chunk

typedef const __attribute__((address_space(1))) void GV;
typedef __attribute__((address_space(3))) void LV;
#define DMA16(g, l) __builtin_amdgcn_global_load_lds((GV*)(g), (LV*)(l), 16, 0, 0)

// Conflicting lanes (32B x-stride) repeat bank classes every 128 B -> they
// differ in byte-offset bits 7-8. XOR those into bank bits 4-5. Involution,
// 16B-aligned blocks move only within their 512B granule.
__device__ __forceinline__ int swz(int o) { return o ^ (((o >> 7) & 3) << 4); }

struct RegSet {
    float4 a0c0, a1c0, w0c0, w1c0, w2c0, w3c0;
    float4 a0c1, a1c1, w0c1, w1c1, w2c1, w3c1;
};

__global__ __launch_bounds__(NTHR, 2) void corr_pipe_kernel(
    const float* __restrict__ in1,
    const float* __restrict__ in2,
    float* __restrict__ out)
{
    __shared__ float lds[NBUF * BUF_FLOATS];   // 73728 B, never zero-inited

    const int tid  = threadIdx.x;
    const int b    = blockIdx.x & 7;            // XCD swizzle: batch pinned to XCD
    const int y0   = (blockIdx.x >> 3) * YB;
    const int lane = tid & 63;
    const int wv   = tid >> 6;                  // 0..8

    // ---- per-lane DMA source (2 slots/wave). Dest LINEAR; source pre-swizzled
    // so LDS[O] holds logical data swz(O) (rule #21 / m173).
    const float* gsrc0;
    const float* gsrc1;
    {
        #define SETUP_SRC(k, gs) {                                              \
            const int O  = (2 * wv + (k)) * 1024 + lane * 16;                   \
            const int Os = swz(O);                                              \
            const int R  = Os / ROWBYTES;                                       \
            const int xb = Os - R * ROWBYTES;                                   \
            const float* p;                                                     \
            if (R >= NROWS) {                                                   \
                p = in1 + (size_t)b * C_ * H_ * W_;  /* dummy, never read */    \
            } else {                                                            \
                const int ch = R / ROWS_PER_CH;                                 \
                const int r  = R - ch * ROWS_PER_CH;                            \
                int row; const float* basep;                                    \
                if (r < YB) { row = y0 + r; basep = in1; }                      \
                else {                                                          \
                    row = y0 + r - 7;            /* yp = y0 + (r-3) - 4 */      \
                    row = row < 0 ? 0 : (row >= H_ ? H_ - 1 : row);             \
                    basep = in2;                 /* OOB rows: garbage, masked */ \
                }                                                               \
                const int xo = (xb < 640) ? (xb >> 2) : 0;  /* pad -> dummy */  \
                p = basep + ((size_t)(b * C_ + ch) * H_ + row) * W_ + xo;       \
            }                                                                   \
            gs = p; }
        SETUP_SRC(0, gsrc0)
        SETUP_SRC(1, gsrc1)
        #undef SETUP_SRC
    }

    // ---- compute-thread coords
    const bool isComp = (tid < NCOMP);
    int ty = 0, dy = 0, xg = 0;
    if (isComp) {
        ty = tid / (ND * NXG);
        const int r2 = tid % (ND * NXG);
        dy = r2 / NXG;
        xg = r2 % NXG;
    }
    const int  ypRow = y0 + ty + dy - 4;
    const bool rowOk = (ypRow >= 0) && (ypRow < H_);
    const int  x0    = xg * TX;

    // ---- per-thread swizzled read offsets (bytes, buffer-local), named scalars
    const int ab0 = ((0 * ROWS_PER_CH + ty) * ROWSTRIDE + x0) * 4;
    const int ab1 = ((1 * ROWS_PER_CH + ty) * ROWSTRIDE + x0) * 4;
    const int wb0 = ((0 * ROWS_PER_CH + YB + ty + dy) * ROWSTRIDE + x0 - 4) * 4;
    const int wb1 = ((1 * ROWS_PER_CH + YB + ty + dy) * ROWSTRIDE + x0 - 4) * 4;
    const int aof00 = swz(ab0), aof01 = swz(ab0 + 16);
    const int aof10 = swz(ab1), aof11 = swz(ab1 + 16);
    const int wof00 = swz(xg == 0 ? wb0 + 16 : wb0);   // clamp (masked anyway)
    const int wof01 = swz(wb0 + 16), wof02 = swz(wb0 + 32), wof03 = swz(wb0 + 48);
    const int wof10 = swz(xg == 0 ? wb1 + 16 : wb1);
    const int wof11 = swz(wb1 + 16), wof12 = swz(wb1 + 32), wof13 = swz(wb1 + 48);

    float acc[ND][TX];
    #pragma unroll
    for (int dx = 0; dx < ND; ++dx)
        #pragma unroll
        for (int j = 0; j < TX; ++j) acc[dx][j] = 0.f;

    RegSet RA, RB;

    #define ISSUE(SLOT) do {                                                  \
        DMA16(gsrc0, &lds[(SLOT) * BUF_FLOATS + (2 * wv) * 256]);             \
        DMA16(gsrc1, &lds[(SLOT) * BUF_FLOATS + (2 * wv + 1) * 256]);         \
        gsrc0 += CHSTEP; gsrc1 += CHSTEP;                                     \
    } while (0);

    #define READBLK(BUFC, R) {                                                \
        const char* bb = (const char*)lds + (BUFC) * BUF_BYTES;               \
        R.a0c0 = *(const float4*)(bb + aof00);                                \
        R.a1c0 = *(const float4*)(bb + aof01);                                \
        R.w0c0 = *(const float4*)(bb + wof00);                                \
        R.w1c0 = *(const float4*)(bb + wof01);                                \
        R.w2c0 = *(const float4*)(bb + wof02);                                \
        R.w3c0 = *(const float4*)(bb + wof03);                                \
        R.a0c1 = *(const float4*)(bb + aof10);                                \
        R.a1c1 = *(const float4*)(bb + aof11);                                \
        R.w0c1 = *(const float4*)(bb + wof10);                                \
        R.w1c1 = *(const float4*)(bb + wof11);                                \
        R.w2c1 = *(const float4*)(bb + wof12);                                \
        R.w3c1 = *(const float4*)(bb + wof13);                                \
    }

    #define FMACH(A0, A1, W0, W1, W2, W3) {                                   \
        float4 w0v = (W0), w3v = (W3);                                        \
        if (xg == 0)       w0v = make_float4(0.f, 0.f, 0.f, 0.f);             \
        if (xg == NXG - 1) w3v = make_float4(0.f, 0.f, 0.f, 0.f);             \
        float a[8]  = {(A0).x, (A0).y, (A0).z, (A0).w,                        \
                       (A1).x, (A1).y, (A1).z, (A1).w};                       \
        float w[16] = {w0v.x, w0v.y, w0v.z, w0v.w,                            \
                       (W1).x, (W1).y, (W1).z, (W1).w,                        \
                       (W2).x, (W2).y, (W2).z, (W2).w,                        \
                       w3v.x, w3v.y, w3v.z, w3v.w};                           \
        _Pragma("unroll")                                                     \
        for (int dx = 0; dx < ND; ++dx) {                                     \
            _Pragma("unroll")                                                 \
            for (int j = 0; j < TX; ++j)                                      \
                acc[dx][j] += a[j] * w[dx + j];                               \
        }                                                                     \
    }

    #define FMABLK(R)                                                         \
        FMACH(R.a0c0, R.a1c0, R.w0c0, R.w1c0, R.w2c0, R.w3c0)                 \
        FMACH(R.a0c1, R.a1c1, R.w0c1, R.w1c1, R.w2c1, R.w3c1)

    // body kc: vmcnt(2) [kc and kc+1 landed]; barrier [all waves' landed, and
    // everyone's reads of kc-1 were drained by their FMA consumption];
    // issue kc+3 [slot (kc-1)&3]; prefetch-read kc+1 -> RDSET; FMA kc (FMSET).
    #define BODY(KMOD4, WN, DOISS, RDSET, FMSET)                              \
        asm volatile("s_waitcnt vmcnt(" WN ")" ::: "memory");                 \
        __builtin_amdgcn_s_barrier();                                         \
        asm volatile("" ::: "memory");                                        \
        if (DOISS) { ISSUE(((KMOD4) + 3) & 3) }                               \
        if (isComp) {                                                         \
            READBLK(((KMOD4) + 1) & 3, RDSET)                                 \
            FMABLK(FMSET)                                                     \
        }

    // ---- prologue: DMA chunks 0,1,2; read chunk 0 into RA
    ISSUE(0)
    ISSUE(1)
    ISSUE(2)
    asm volatile("s_waitcnt vmcnt(4)" ::: "memory");   // chunk 0 landed
    __builtin_amdgcn_s_barrier();
    asm volatile("" ::: "memory");
    if (isComp) { READBLK(0, RA) }

    // ---- main loop: kc = 0..123 (even kc: FMA RA / read RB; odd: swapped)
    #pragma unroll 1
    for (int g = 0; g < 31; ++g) {
        BODY(0, "2", true, RB, RA)
        BODY(1, "2", true, RA, RB)
        BODY(2, "2", true, RB, RA)
        BODY(3, "2", true, RA, RB)
    }
    // ---- tail: kc = 124..127
    BODY(0, "2", true,  RB, RA)   // kc=124, issues chunk 127
    BODY(1, "2", false, RA, RB)   // kc=125
    BODY(2, "0", false, RB, RA)   // kc=126, reads 127 -> RB
    asm volatile("" ::: "memory");
    if (isComp) { FMABLK(RB) }    // kc=127

    #undef BODY
    #undef FMABLK
    #undef FMACH
    #undef READBLK
    #undef ISSUE

    // ---- epilogue: OOB-dy rows produce zeros (multiply by masked scale)
    if (isComp) {
        const float m = rowOk ? (1.0f / (float)C_) : 0.f;
        float* outp = out + ((size_t)(b * NDISP + dy * ND) * H_ + (y0 + ty)) * W_ + x0;
        #pragma unroll
        for (int dx = 0; dx < ND; ++dx) {
            float4 o0 = make_float4(acc[dx][0] * m, acc[dx][1] * m,
                                    acc[dx][2] * m, acc[dx][3] * m);
            float4 o1 = make_float4(acc[dx][4] * m, acc[dx][5] * m,
                                    acc[dx][6] * m, acc[dx][7] * m);
            *(float4*)(outp + dx * (H_ * W_))     = o0;
            *(float4*)(outp + dx * (H_ * W_) + 4) = o1;
        }
    }
}

extern "C" void kernel_launch(void* const* d_in, const int* in_sizes, int n_in,
                              void* d_out, int out_size, void* d_ws, size_t ws_size,
                              hipStream_t stream) {
    const float* in1 = (const float*)d_in[0];
    const float* in2 = (const float*)d_in[1];
    float* out = (float*)d_out;

    const int grid = B_ * (H_ / YB);   // 256 blocks = 1 per CU
    corr_pipe_kernel<<<grid, NTHR, 0, stream>>>(in1, in2, out);
}

// Round 9
// 150.969 us; speedup vs baseline: 6.0244x; 6.0244x over previous
//
#include <hip/hip_runtime.h>
#include <stdint.h>

#define B_ 8
#define C_ 256
#define H_ 96
#define W_ 160
#define ND 9
#define NDISP 81
#define CK 2                   // channels per chunk
#define NCHUNK (C_ / CK)       // 128
#define TX 8
#define NXG (W_ / TX)          // 20
#define NTHR 192               // 3 waves
#define NCOMP (ND * NXG)       // 180 compute threads
#define ROWS_PER_CH 10         // 1 in1 row + 9 in2 rows (YB=1)
#define NROWS (CK * ROWS_PER_CH)  // 20
// INVARIANT: row stride must be a multiple of the 16B DMA width, else DMA
// blocks straddle row boundaries (R8: corrupt odd rows + OOB at buffer end).
#define STRF 172               // floats per row slot (688 B = 43*16)
#define ROWB 688
#define BUF_B 15360            // 15 x 1024B DMA slots (>= 20*688=13760); %512==0
#define BUF_F 3840
#define NBUF 3                 // depth-2 prefetch; 46080 B -> 3 blocks/CU
#define CHSTEP (CK * H_ * W_)  // global float step per chunk

typedef const __attribute__((address_space(1))) void GV;
typedef __attribute__((address_space(3))) void LV;
#define DMA16(g, l) __builtin_amdgcn_global_load_lds((GV*)(g), (LV*)(l), 16, 0, 0)

// 32B-stride lanes repeat bank classes every 128 B (addr bits 7-8) -> XOR
// those into bank bits 4-5. Involution within 512B windows, 16B-preserving.
__device__ __forceinline__ int swz(int o) { return o ^ (((o >> 7) & 3) << 4); }

// Map a physical LDS byte offset O to its global source (pre-swizzled source:
// LDS[O] holds logical data swz(O); readers use swz(logical)).
__device__ __forceinline__ const float* decode_src(int O, int b, int y,
        const float* in1, const float* in2)
{
    const int Os = swz(O);
    const int R  = Os / ROWB;
    const int xb = Os - R * ROWB;          // multiple of 16 (ROWB%16==0)
    if (R >= NROWS) return in1;            // dummy slot tail, never read logically
    const int ch = R / ROWS_PER_CH;
    const int r  = R - ch * ROWS_PER_CH;
    const float* basep;
    int row;
    if (r == 0) { basep = in1; row = y; }  // in1 row y
    else {                                 // in2 row y + dy - 4, dy = r-1
        row = y + (r - 1) - 4;
        row = row < 0 ? 0 : (row >= H_ ? H_ - 1 : row);  // clamped; masked later
        basep = in2;
    }
    // xb<640: read [xb, xb+16) ends <= 640 = row byte size -> never OOB.
    const int xo = (xb < 640) ? (xb >> 2) : 0;           // row pad -> dummy
    return basep + ((size_t)(b * C_ + ch) * H_ + row) * W_ + xo;
}

__global__ __launch_bounds__(NTHR) void corr3_kernel(
    const float* __restrict__ in1,
    const float* __restrict__ in2,
    float* __restrict__ out)
{
    __shared__ float lds[NBUF * BUF_F];   // 46080 B, never zero-inited

    const int tid  = threadIdx.x;
    const int b    = blockIdx.x & 7;      // XCD swizzle: batch pinned to XCD
    const int y    = blockIdx.x >> 3;
    const int lane = tid & 63;
    const int wv   = tid >> 6;            // 0..2; wave wv owns slots wv+3k

    // ---- per-lane DMA sources, 5 uniform slots per wave
    const float* g0 = decode_src((wv +  0) * 1024 + lane * 16, b, y, in1, in2);
    const float* g1 = decode_src((wv +  3) * 1024 + lane * 16, b, y, in1, in2);
    const float* g2 = decode_src((wv +  6) * 1024 + lane * 16, b, y, in1, in2);
    const float* g3 = decode_src((wv +  9) * 1024 + lane * 16, b, y, in1, in2);
    const float* g4 = decode_src((wv + 12) * 1024 + lane * 16, b, y, in1, in2);

    // ---- compute coords: dy-major (lanes 0-19 = dy0 ... -> a-row broadcasts)
    const bool isComp = (tid < NCOMP);
    const int  dy = tid / NXG;            // 0..8
    const int  xg = tid % NXG;            // 0..19
    const int  x0 = xg * TX;
    const bool rowOk = isComp && (y + dy - 4 >= 0) && (y + dy - 4 < H_);

    // ---- swizzled read offsets (bytes, buffer-local), named scalars
    const int ab0 = (0 * ROWS_PER_CH * STRF + x0) * 4;
    const int ab1 = (1 * ROWS_PER_CH * STRF + x0) * 4;
    const int wb0 = ((0 * ROWS_PER_CH + 1 + dy) * STRF + x0 - 4) * 4;
    const int wb1 = ((1 * ROWS_PER_CH + 1 + dy) * STRF + x0 - 4) * 4;
    const int aof00 = swz(ab0), aof01 = swz(ab0 + 16);
    const int aof10 = swz(ab1), aof11 = swz(ab1 + 16);
    const int wof00 = swz(xg == 0 ? wb0 + 16 : wb0);   // xg==0: avoid byte -16
    const int wof01 = swz(wb0 + 16);
    const int wof02 = swz(wb0 + 32), wof03 = swz(wb0 + 48);
    const int wof10 = swz(xg == 0 ? wb1 + 16 : wb1);
    const int wof11 = swz(wb1 + 16);
    const int wof12 = swz(wb1 + 32), wof13 = swz(wb1 + 48);

    float acc[ND][TX];
    #pragma unroll
    for (int dx = 0; dx < ND; ++dx)
        #pragma unroll
        for (int j = 0; j < TX; ++j) acc[dx][j] = 0.f;

    #define ISSUE(BUF) do {                                                   \
        float* lb = &lds[(BUF) * BUF_F];                                      \
        DMA16(g0, lb + (wv +  0) * 256);                                      \
        DMA16(g1, lb + (wv +  3) * 256);                                      \
        DMA16(g2, lb + (wv +  6) * 256);                                      \
        DMA16(g3, lb + (wv +  9) * 256);                                      \
        DMA16(g4, lb + (wv + 12) * 256);                                      \
        g0 += CHSTEP; g1 += CHSTEP; g2 += CHSTEP; g3 += CHSTEP; g4 += CHSTEP; \
    } while (0);

    #define FMACH(A0, A1, W0, W1, W2, W3) {                                   \
        float4 w0v = (W0), w3v = (W3);                                        \
        if (xg == 0)       w0v = make_float4(0.f, 0.f, 0.f, 0.f);             \
        if (xg == NXG - 1) w3v = make_float4(0.f, 0.f, 0.f, 0.f);             \
        float a[8]  = {(A0).x, (A0).y, (A0).z, (A0).w,                        \
                       (A1).x, (A1).y, (A1).z, (A1).w};                       \
        float w[16] = {w0v.x, w0v.y, w0v.z, w0v.w,                            \
                       (W1).x, (W1).y, (W1).z, (W1).w,                        \
                       (W2).x, (W2).y, (W2).z, (W2).w,                        \
                       w3v.x, w3v.y, w3v.z, w3v.w};                           \
        _Pragma("unroll")                                                     \
        for (int dx = 0; dx < ND; ++dx) {                                     \
            _Pragma("unroll")                                                 \
            for (int j = 0; j < TX; ++j)                                      \
                acc[dx][j] += a[j] * w[dx + j];                               \
        }                                                                     \
    }

    #define COMPUTE(BUF)                                                      \
    if (isComp) {                                                             \
        const char* bb = (const char*)lds + (BUF) * BUF_B;                    \
        {                                                                     \
            float4 a0 = *(const float4*)(bb + aof00);                         \
            float4 a1 = *(const float4*)(bb + aof01);                         \
            float4 w0 = *(const float4*)(bb + wof00);                         \
            float4 w1 = *(const float4*)(bb + wof01);                         \
            float4 w2 = *(const float4*)(bb + wof02);                         \
            float4 w3 = *(const float4*)(bb + wof03);                         \
            FMACH(a0, a1, w0, w1, w2, w3)                                     \
        }                                                                     \
        {                                                                     \
            float4 a0 = *(const float4*)(bb + aof10);                         \
            float4 a1 = *(const float4*)(bb + aof11);                         \
            float4 w0 = *(const float4*)(bb + wof10);                         \
            float4 w1 = *(const float4*)(bb + wof11);                         \
            float4 w2 = *(const float4*)(bb + wof12);                         \
            float4 w3 = *(const float4*)(bb + wof13);                         \
            FMACH(a0, a1, w0, w1, w2, w3)                                     \
        }                                                                     \
    }

    // body kc: vmcnt(5) [own kc slots landed; kc+1 in flight]; barrier [all
    // waves' kc landed AND all reads of kc-1 drained (consumed by FMAs)];
    // issue kc+2 into buffer (kc+2)%3 = (kc-1)%3 [just freed]; compute kc.
    #define BODY(KMOD3, WN, DOISS)                                            \
        asm volatile("s_waitcnt vmcnt(" WN ")" ::: "memory");                 \
        __builtin_amdgcn_s_barrier();                                         \
        asm volatile("" ::: "memory");                                        \
        __builtin_amdgcn_sched_barrier(0);                                    \
        if (DOISS) { ISSUE(((KMOD3) + 2) % 3) }                               \
        COMPUTE(KMOD3)

    // ---- prologue: DMA chunks 0,1 into buffers 0,1 (10 outstanding/wave)
    ISSUE(0)
    ISSUE(1)

    // ---- main loop: kc = 0..125
    #pragma unroll 1
    for (int g = 0; g < 42; ++g) {
        BODY(0, "5", true)
        BODY(1, "5", true)
        BODY(2, "5", true)
    }
    // ---- tail: kc = 126 (127 in flight), kc = 127
    BODY(0, "5", false)
    BODY(1, "0", false)

    #undef BODY
    #undef COMPUTE
    #undef FMACH
    #undef ISSUE

    // ---- epilogue: OOB-dy rows output zeros (masked scale; staged garbage
    // was clamped real data -> finite, so 0-scale is exact)
    if (isComp) {
        const float m = rowOk ? (1.0f / (float)C_) : 0.f;
        float* outp = out + ((size_t)(b * NDISP + dy * ND) * H_ + y) * W_ + x0;
        #pragma unroll
        for (int dx = 0; dx < ND; ++dx) {
            float4 o0 = make_float4(acc[dx][0] * m, acc[dx][1] * m,
                                    acc[dx][2] * m, acc[dx][3] * m);
            float4 o1 = make_float4(acc[dx][4] * m, acc[dx][5] * m,
                                    acc[dx][6] * m, acc[dx][7] * m);
            *(float4*)(outp + dx * (H_ * W_))     = o0;
            *(float4*)(outp + dx * (H_ * W_) + 4) = o1;
        }
    }
}

extern "C" void kernel_launch(void* const* d_in, const int* in_sizes, int n_in,
                              void* d_out, int out_size, void* d_ws, size_t ws_size,
                              hipStream_t stream) {
    const float* in1 = (const float*)d_in[0];
    const float* in2 = (const float*)d_in[1];
    float* out = (float*)d_out;

    const int grid = B_ * H_;   // 768 blocks = 3 per CU (45 KB LDS each)
    corr3_kernel<<<grid, NTHR, 0, stream>>>(in1, in2, out);
}